// Round 9
// baseline (1773.328 us; speedup 1.0000x reference)
//
#include <hip/hip_runtime.h>
#include <hip/hip_bf16.h>

#define BATCH 4
#define SEQ   4096
#define BS_TOK (BATCH*SEQ)   // 16384 rows
#define EMB   512
#define NH    8
#define HD    64
#define FF    2048
#define NL    6

typedef unsigned short u16;
typedef __attribute__((ext_vector_type(8))) short bf16x8;
typedef __attribute__((ext_vector_type(4))) float f32x4;

__device__ __forceinline__ float bf2f(u16 u) {
    union { unsigned int i; float f; } x; x.i = ((unsigned int)u) << 16; return x.f;
}
__device__ __forceinline__ u16 f2bf(float f) {
    __hip_bfloat16 b = __float2bfloat16(f);
    return *(u16*)&b;
}
// gelu(x) = 0.5x(1+tanh(z)), z=0.79788456(x+0.044715x^3)  ==  x / (1+e^{-2z})
__device__ __forceinline__ float gelu_fast(float x) {
    float e = __expf(x * (-1.5957691216057308f - 0.0713548162726009f * x * x));
    return x * __builtin_amdgcn_rcpf(1.f + e);
}
__device__ __forceinline__ void store_out(float* p, float v) { *p = v; }
__device__ __forceinline__ void store_out(u16* p, float v) { *p = f2bf(v); }
__device__ __forceinline__ void store_pair(float* p, float a, float b) {
    *(float2*)p = make_float2(a, b);
}
__device__ __forceinline__ void store_pair(u16* p, float a, float b) {
    unsigned int u = ((unsigned int)f2bf(b) << 16) | (unsigned int)f2bf(a);
    *(unsigned int*)p = u;
}

__device__ __forceinline__ void gl_lds16(const void* g, void* l) {
    __builtin_amdgcn_global_load_lds(
        (__attribute__((address_space(1))) void*)g,
        (__attribute__((address_space(3))) void*)l, 16, 0, 0);
}

// ---------------------------------------------------------------------------
__global__ __launch_bounds__(128) void embed_kernel(
        const int* __restrict__ tok, const float* __restrict__ emb,
        float* __restrict__ X, float* __restrict__ maskf) {
    int row = blockIdx.x;
    int t = threadIdx.x;
    int id = tok[row];
    if (t == 0) maskf[row] = (id > 0) ? 1.f : 0.f;
    int s = row & (SEQ - 1);
    int e0 = t * 4;
    float4 u = *(const float4*)(emb + (size_t)id * EMB + e0);
    float vals[4] = { u.x, u.y, u.z, u.w };
    float out[4];
#pragma unroll
    for (int j = 0; j < 4; ++j) {
        int ee = e0 + j;
        int i = ee >> 1;
        float div = expf(-0.035977892078031970f * (float)i);
        float ang = (float)s * div;
        float pe = (ee & 1) ? cosf(ang) : sinf(ang);
        out[j] = vals[j] + pe;
    }
    *(float4*)(X + (size_t)row * EMB + e0) = make_float4(out[0], out[1], out[2], out[3]);
}

// ---------------------------------------------------------------------------
// LN row kernel, vectorized (G13): float2 loads of x/sc/bi, packed 4B stores.
// ---------------------------------------------------------------------------
template<typename OUT>
__global__ __launch_bounds__(256) void ln_kernel(
        const float* __restrict__ X, const float* __restrict__ sc,
        const float* __restrict__ bi, OUT* __restrict__ Y) {
    int row = blockIdx.x, t = threadIdx.x;
    const float* x = X + (size_t)row * EMB;
    float2 v = *(const float2*)(x + 2 * t);
    float a = v.x, b = v.y;
    float s = a + b, q = a * a + b * b;
#pragma unroll
    for (int off = 32; off; off >>= 1) {
        s += __shfl_xor(s, off);
        q += __shfl_xor(q, off);
    }
    __shared__ float ss[4], qq[4];
    int w = t >> 6;
    if ((t & 63) == 0) { ss[w] = s; qq[w] = q; }
    __syncthreads();
    s = ss[0] + ss[1] + ss[2] + ss[3];
    q = qq[0] + qq[1] + qq[2] + qq[3];
    float mu = s * (1.f / 512.f);
    float var = q * (1.f / 512.f) - mu * mu;
    float rstd = rsqrtf(var + 1e-6f);
    float2 scv = *(const float2*)(sc + 2 * t);
    float2 biv = *(const float2*)(bi + 2 * t);
    float y0 = (a - mu) * rstd * scv.x + biv.x;
    float y1 = (b - mu) * rstd * scv.y + biv.y;
    store_pair(&Y[(size_t)row * EMB + 2 * t], y0, y1);
}

// ---------------------------------------------------------------------------
// Weight transpose + bf16 cast: W[K][N] f32 -> WT[N][K] bf16; z picks source
// ---------------------------------------------------------------------------
__global__ __launch_bounds__(256) void transpose_w(
        const float* __restrict__ W0, const float* __restrict__ W1,
        const float* __restrict__ W2, const float* __restrict__ W3,
        u16* __restrict__ WT, int K, int N) {
    const float* W = (blockIdx.z == 0) ? W0 : (blockIdx.z == 1) ? W1
                   : (blockIdx.z == 2) ? W2 : W3;
    u16* dst = WT + (size_t)blockIdx.z * K * N;
    __shared__ u16 tile[32][33];
    int n0 = blockIdx.x * 32, k0 = blockIdx.y * 32;
    int tx = threadIdx.x & 31, ty = threadIdx.x >> 5;
#pragma unroll
    for (int u = 0; u < 4; ++u)
        tile[ty + u * 8][tx] = f2bf(W[(size_t)(k0 + ty + u * 8) * N + n0 + tx]);
    __syncthreads();
#pragma unroll
    for (int u = 0; u < 4; ++u)
        dst[(size_t)(n0 + ty + u * 8) * K + k0 + tx] = tile[tx][ty + u * 8];
}

// ---------------------------------------------------------------------------
// 2-phase MFMA bf16 GEMM (measured-best config, r5/r7): tile 128x128, 4 waves,
// BK=32 double-buffer, stage-early, one __syncthreads per step.  Used for the
// N=512 GEMMs (WO, FFN2) where the 256-tile kernel's grid would be too small.
// ---------------------------------------------------------------------------
template<int OP, typename OUT>
__global__ __launch_bounds__(256, 4) void mfma_gemm(
        const u16* __restrict__ A, const u16* __restrict__ BT,
        const float* __restrict__ bias, const float* __restrict__ rowscale,
        const float* __restrict__ residual, OUT* __restrict__ C,
        int K, int lda, int ldb, int ldc) {
    __shared__ u16 As[2][128 * 32];   // buffer bb: [128 rows][32 k] (64B rows)
    __shared__ u16 Bs[2][128 * 32];
    int tid = threadIdx.x;
    int wid = tid >> 6, lane = tid & 63;
    int nwg = gridDim.x * gridDim.y;
    int lin = blockIdx.y * gridDim.x + blockIdx.x;
    int swz = (nwg & 7) ? lin : ((lin & 7) * (nwg >> 3) + (lin >> 3));
    int bx = swz % gridDim.x, by = swz / gridDim.x;
    int row0 = by * 128, col0 = bx * 128;
    int wm = (wid & 1) * 64, wn = (wid >> 1) * 64;
    int quad = lane >> 4, l16 = lane & 15;

    f32x4 acc[4][4];
#pragma unroll
    for (int i = 0; i < 4; ++i)
#pragma unroll
        for (int j = 0; j < 4; ++j)
#pragma unroll
            for (int r = 0; r < 4; ++r) acc[i][j][r] = 0.f;

    int rsub = lane >> 2;
    int koff = (lane & 3) * 8;
    const u16* gA = A  + (size_t)(row0 + wid * 16 + rsub) * lda + koff;
    const u16* gB = BT + (size_t)(col0 + wid * 16 + rsub) * ldb + koff;

    auto stage = [&](int bb, int kk) {
        u16* lA = As[bb] + wid * 512;
        u16* lB = Bs[bb] + wid * 512;
#pragma unroll
        for (int i = 0; i < 2; ++i) {
            gl_lds16(gA + (size_t)(i * 64) * lda + kk, lA + i * 2048);
            gl_lds16(gB + (size_t)(i * 64) * ldb + kk, lB + i * 2048);
        }
    };

    int nt = K >> 5;           // BK=32 steps
    stage(0, 0);
    __syncthreads();           // drain prologue loads
    for (int t = 0; t < nt; ++t) {
        int cur = t & 1;
        if (t + 1 < nt) stage(cur ^ 1, (t + 1) * 32);   // issue next tile EARLY
        bf16x8 af[4], bfv[4];
#pragma unroll
        for (int i = 0; i < 4; ++i)
            af[i] = *(const bf16x8*)(As[cur] + (wm + i * 16 + l16) * 32 + quad * 8);
#pragma unroll
        for (int j = 0; j < 4; ++j)
            bfv[j] = *(const bf16x8*)(Bs[cur] + (wn + j * 16 + l16) * 32 + quad * 8);
#pragma unroll
        for (int i = 0; i < 4; ++i)
#pragma unroll
            for (int j = 0; j < 4; ++j)
                acc[i][j] = __builtin_amdgcn_mfma_f32_16x16x32_bf16(af[i], bfv[j], acc[i][j], 0, 0, 0);
        __syncthreads();
    }

    // epilogue: D mapping col = lane&15, row = quad*4 + reg (m89-verified)
    int seg = col0 >> 9;
    float bc[4];
#pragma unroll
    for (int j = 0; j < 4; ++j)
        bc[j] = bias ? bias[col0 + wn + j * 16 + l16] : 0.f;
#pragma unroll
    for (int i = 0; i < 4; ++i) {
        float res[4][4];
        if (residual) {
#pragma unroll
            for (int r = 0; r < 4; ++r) {
                size_t rb = (size_t)(row0 + wm + i * 16 + quad * 4 + r) * ldc + col0 + wn;
#pragma unroll
                for (int j = 0; j < 4; ++j)
                    res[r][j] = residual[rb + j * 16 + l16];
            }
        }
#pragma unroll
        for (int r = 0; r < 4; ++r) {
            int row = row0 + wm + i * 16 + quad * 4 + r;
            float rsv = (OP == 3 && seg == 1) ? rowscale[row] : 1.f;
            size_t rb = (size_t)row * ldc + col0 + wn;
#pragma unroll
            for (int j = 0; j < 4; ++j) {
                float val = acc[i][j][r] + bc[j];
                if (OP == 1) val = gelu_fast(val);
                if (OP == 3 && seg < 2) val = fmaxf(val, 0.f) + 1e-3f;
                if (OP == 3 && seg == 1) val *= rsv;
                size_t idx = rb + j * 16 + l16;
                if (residual) val += res[r][j];
                store_out(&C[idx], val);
            }
        }
    }
}

// ---------------------------------------------------------------------------
// Deep-pipeline MFMA GEMM for the big shapes (K=512 fixed): tile 256x256,
// 8 waves (2M x 4N, 512 thr), per-wave output 128x64 (acc 8x4), BK=64.
// LDS: 2 buffers x (A,B) x [2 planes][256 rows][32 k] = 128 KB -> 1 blk/CU.
// Per iteration (one K-tile of 64):
//   vmcnt(8) [tile kt long-landed; kt+1's 8 loads stay in flight] ; s_barrier
//   read B frags (8 ds_read_b128); 4 phases of {A-quad reads, 16 MFMA}
//     -> 64 MFMA between barriers, phases separated only by compiler lgkmcnt
//   s_barrier  [all waves' reads of this buffer done]
//   stage tile kt+2 into THIS buffer (8 gl_lds/thread) -> full-iteration
//     prefetch distance, so the vmcnt at consumption waits on landed loads.
// Invariants: per-wave vmcnt + barrier1 => all stage-kt data visible;
// lgkmcnt-before-MFMA + barrier2 => buffer free before re-stage; stage kt+1
// writes target the other buffer.  All LDS addressing compile-time static
// (two explicit buffer bodies; r6 lesson: runtime %3 indexing = VALU blowup).
// Staging linearity: LDS u16 offset = pl*8192 + hf*4096 + tid*8 (lane-linear
// within wave, wave-uniform base) <=> layout [pl][row][32] with row=hf*128+
// (tid>>2), k=(tid&3)*8 -- verified bijective.
// ---------------------------------------------------------------------------
template<int OP, typename OUT>
__global__ __launch_bounds__(512, 2) void mfma_gemm_big(
        const u16* __restrict__ A, const u16* __restrict__ BT,
        const float* __restrict__ bias, const float* __restrict__ rowscale,
        const float* __restrict__ residual, OUT* __restrict__ C,
        int lda, int ldb, int ldc) {
    constexpr int NKT = 8;            // K = 512 = 8 x 64
    __shared__ u16 As[2][2 * 256 * 32];
    __shared__ u16 Bs[2][2 * 256 * 32];
    int tid = threadIdx.x;
    int wid = tid >> 6, lane = tid & 63;
    int nwg = gridDim.x * gridDim.y;
    int lin = blockIdx.y * gridDim.x + blockIdx.x;
    int swz = (nwg & 7) ? lin : ((lin & 7) * (nwg >> 3) + (lin >> 3));
    int bx = swz % gridDim.x, by = swz / gridDim.x;
    int row0 = by * 256, col0 = bx * 256;
    int wm = (wid & 1) * 128;         // wave M offset (rows)
    int wn = (wid >> 1) * 64;         // wave N offset (cols)
    int quad = lane >> 4, l16 = lane & 15;

    f32x4 acc[8][4];
#pragma unroll
    for (int i = 0; i < 8; ++i)
#pragma unroll
        for (int j = 0; j < 4; ++j)
#pragma unroll
            for (int r = 0; r < 4; ++r) acc[i][j][r] = 0.f;

    // staging: thread t covers row hf*128 + (t>>2), k-piece pl*32 + (t&3)*8
    int srow = tid >> 2;
    int skp  = (tid & 3) * 8;
    const u16* gA = A  + (size_t)(row0 + srow) * lda + skp;
    const u16* gB = BT + (size_t)(col0 + srow) * ldb + skp;

    auto stage = [&](u16* lA, u16* lB, int k0) {
#pragma unroll
        for (int pl = 0; pl < 2; ++pl)
#pragma unroll
            for (int hf = 0; hf < 2; ++hf) {
                int ldsoff = pl * 8192 + hf * 4096 + tid * 8;
                gl_lds16(gA + (size_t)(hf * 128) * lda + k0 + pl * 32, lA + ldsoff);
                gl_lds16(gB + (size_t)(hf * 128) * ldb + k0 + pl * 32, lB + ldsoff);
            }
    };

    auto iter = [&](const u16* lA, const u16* lB, u16* sA, u16* sB, int kt) {
        if (kt < NKT - 1) asm volatile("s_waitcnt vmcnt(8)" ::: "memory");
        else              asm volatile("s_waitcnt vmcnt(0)" ::: "memory");
        __builtin_amdgcn_s_barrier();
        asm volatile("" ::: "memory");
        bf16x8 bfv[4][2];
#pragma unroll
        for (int nf = 0; nf < 4; ++nf)
#pragma unroll
            for (int p = 0; p < 2; ++p)
                bfv[nf][p] = *(const bf16x8*)(lB + p * 8192 + (wn + nf * 16 + l16) * 32 + quad * 8);
#pragma unroll
        for (int q = 0; q < 4; ++q) {
            bf16x8 af[2][2];
#pragma unroll
            for (int mf = 0; mf < 2; ++mf)
#pragma unroll
                for (int p = 0; p < 2; ++p)
                    af[mf][p] = *(const bf16x8*)(lA + p * 8192 + (wm + (q * 2 + mf) * 16 + l16) * 32 + quad * 8);
            __builtin_amdgcn_s_setprio(1);
#pragma unroll
            for (int mf = 0; mf < 2; ++mf)
#pragma unroll
                for (int nf = 0; nf < 4; ++nf) {
                    acc[q * 2 + mf][nf] = __builtin_amdgcn_mfma_f32_16x16x32_bf16(
                        af[mf][0], bfv[nf][0], acc[q * 2 + mf][nf], 0, 0, 0);
                    acc[q * 2 + mf][nf] = __builtin_amdgcn_mfma_f32_16x16x32_bf16(
                        af[mf][1], bfv[nf][1], acc[q * 2 + mf][nf], 0, 0, 0);
                }
            __builtin_amdgcn_s_setprio(0);
        }
        asm volatile("" ::: "memory");
        __builtin_amdgcn_s_barrier();
        asm volatile("" ::: "memory");
        if (kt + 2 < NKT) stage(sA, sB, (kt + 2) * 64);
    };

    stage(As[0], Bs[0], 0);
    stage(As[1], Bs[1], 64);
#pragma unroll 1
    for (int kt = 0; kt < NKT; kt += 2) {
        iter(As[0], Bs[0], As[0], Bs[0], kt);
        iter(As[1], Bs[1], As[1], Bs[1], kt + 1);
    }

    // epilogue: D mapping col = lane&15, row = quad*4 + reg (m89-verified)
    int seg = col0 >> 9;   // uniform per block (col0 % 256 == 0, 512 % 256 == 0)
    float bc[4];
#pragma unroll
    for (int nf = 0; nf < 4; ++nf)
        bc[nf] = bias ? bias[col0 + wn + nf * 16 + l16] : 0.f;
#pragma unroll
    for (int ifr = 0; ifr < 8; ++ifr) {
#pragma unroll
        for (int r = 0; r < 4; ++r) {
            int row = row0 + wm + ifr * 16 + quad * 4 + r;
            float rsv = (OP == 3 && seg == 1) ? rowscale[row] : 1.f;
            size_t rb = (size_t)row * ldc + col0 + wn;
#pragma unroll
            for (int nf = 0; nf < 4; ++nf) {
                float val = acc[ifr][nf][r] + bc[nf];
                if (OP == 1) val = gelu_fast(val);
                if (OP == 3 && seg < 2) val = fmaxf(val, 0.f) + 1e-3f;
                if (OP == 3 && seg == 1) val *= rsv;
                size_t idx = rb + nf * 16 + l16;
                if (residual) val += residual[idx];
                store_out(&C[idx], val);
            }
        }
    }
}

// ---------------------------------------------------------------------------
// MFMA kv-reduce: kv[bh][m][d] = sum_s PK[s][m]*V[s][d]; z[bh][m] = sum_s PK[s][m]
// ---------------------------------------------------------------------------
__global__ __launch_bounds__(256) void kv_reduce_mfma(
        const u16* __restrict__ PK, const u16* __restrict__ V,
        float* __restrict__ KV, float* __restrict__ Z, int ld) {
    __shared__ __align__(16) u16 pks[32][68];
    __shared__ __align__(16) u16 vvs[32][68];
    int bh = blockIdx.x;
    int b = bh >> 3, hh = bh & 7;
    int cc = blockIdx.y;
    int t = threadIdx.x;
    int wid = t >> 6, lane = t & 63;
    int quad = lane >> 4, l16 = lane & 15;
    int wm = (wid & 1) * 32, wd = (wid >> 1) * 32;

    f32x4 acc[2][2];
    f32x4 zacc[2];
#pragma unroll
    for (int i = 0; i < 2; ++i) {
#pragma unroll
        for (int j = 0; j < 2; ++j)
#pragma unroll
            for (int r = 0; r < 4; ++r) acc[i][j][r] = 0.f;
#pragma unroll
        for (int r = 0; r < 4; ++r) zacc[i][r] = 0.f;
    }
    bf16x8 ones;
#pragma unroll
    for (int e = 0; e < 8; ++e) ones[e] = (short)0x3F80;   // bf16 1.0

    int s_l = t >> 3, mo = (t & 7) * 8;
    const u16* gP = PK + (size_t)(b * SEQ + cc * 256 + s_l) * ld + hh * 64 + mo;
    const u16* gV = V  + (size_t)(b * SEQ + cc * 256 + s_l) * ld + hh * 64 + mo;
    ushort4 p0 = *(const ushort4*)gP;
    ushort4 p1 = *(const ushort4*)(gP + 4);
    ushort4 q0 = *(const ushort4*)gV;
    ushort4 q1 = *(const ushort4*)(gV + 4);

    for (int st = 0; st < 8; ++st) {
        *(ushort4*)&pks[s_l][mo]     = p0;
        *(ushort4*)&pks[s_l][mo + 4] = p1;
        *(ushort4*)&vvs[s_l][mo]     = q0;
        *(ushort4*)&vvs[s_l][mo + 4] = q1;
        __syncthreads();
        if (st < 7) {
            gP += (size_t)32 * ld;  gV += (size_t)32 * ld;
            p0 = *(const ushort4*)gP;  p1 = *(const ushort4*)(gP + 4);
            q0 = *(const ushort4*)gV;  q1 = *(const ushort4*)(gV + 4);
        }
        bf16x8 af[2], bfv[2];
#pragma unroll
        for (int i = 0; i < 2; ++i) {
#pragma unroll
            for (int e = 0; e < 8; ++e) {
                af[i][e]  = (short)pks[quad * 8 + e][wm + i * 16 + l16];
                bfv[i][e] = (short)vvs[quad * 8 + e][wd + i * 16 + l16];
            }
        }
#pragma unroll
        for (int i = 0; i < 2; ++i)
#pragma unroll
            for (int j = 0; j < 2; ++j)
                acc[i][j] = __builtin_amdgcn_mfma_f32_16x16x32_bf16(af[i], bfv[j], acc[i][j], 0, 0, 0);
        if (wid < 2) {
            zacc[0] = __builtin_amdgcn_mfma_f32_16x16x32_bf16(af[0], ones, zacc[0], 0, 0, 0);
            zacc[1] = __builtin_amdgcn_mfma_f32_16x16x32_bf16(af[1], ones, zacc[1], 0, 0, 0);
        }
        __syncthreads();
    }

#pragma unroll
    for (int i = 0; i < 2; ++i)
#pragma unroll
        for (int j = 0; j < 2; ++j)
#pragma unroll
            for (int r = 0; r < 4; ++r)
                atomicAdd(&KV[((size_t)bh * 64 + wm + i * 16 + quad * 4 + r) * 64
                              + wd + j * 16 + l16], acc[i][j][r]);
    if (wid < 2 && l16 == 0) {
#pragma unroll
        for (int i = 0; i < 2; ++i)
#pragma unroll
            for (int r = 0; r < 4; ++r)
                atomicAdd(&Z[(size_t)bh * 64 + wm + i * 16 + quad * 4 + r], zacc[i][r]);
    }
}

// ---------------------------------------------------------------------------
// out[b,s,h,d] = (phi_q . kv[:,d]) / (phi_q . z);  PQ strided by ld
// ---------------------------------------------------------------------------
__global__ __launch_bounds__(256) void attn_out2(
        const u16* __restrict__ PQ, const float* __restrict__ KV,
        const float* __restrict__ Z, u16* __restrict__ O, int ld) {
    __shared__ float kvT[64 * 65];
    __shared__ float zsh[64];
    __shared__ float phs[4][72];
    int hh = blockIdx.y;
    int row0 = blockIdx.x * 32;
    int b = row0 >> 12;
    int bh = b * NH + hh;
    int t = threadIdx.x;
    const float* kvg = KV + (size_t)bh * 4096;
#pragma unroll
    for (int u = 0; u < 16; ++u) {
        int idx = u * 256 + t;
        kvT[(idx & 63) * 65 + (idx >> 6)] = kvg[idx];
    }
    if (t < 64) zsh[t] = Z[(size_t)bh * 64 + t];
    __syncthreads();
    int wid = t >> 6, lane = t & 63;
    const float* kvrow = kvT + lane * 65;
    for (int rr = 0; rr < 8; ++rr) {
        int row = row0 + wid * 8 + rr;
        float p = bf2f(PQ[(size_t)row * ld + hh * 64 + lane]);
        float d = p * zsh[lane];
#pragma unroll
        for (int off = 32; off; off >>= 1) d += __shfl_xor(d, off);
        d = fmaxf(d, 1e-20f);
        phs[wid][lane] = p;
        float acc = 0.f;
#pragma unroll
        for (int mm = 0; mm < 64; ++mm)
            acc = fmaf(phs[wid][mm], kvrow[mm], acc);
        O[(size_t)row * EMB + hh * 64 + lane] = f2bf(acc / d);
    }
}

// ---------------------------------------------------------------------------
extern "C" void kernel_launch(void* const* d_in, const int* in_sizes, int n_in,
                              void* d_out, int out_size, void* d_ws, size_t ws_size,
                              hipStream_t stream) {
    (void)in_sizes; (void)n_in; (void)out_size; (void)ws_size;
    const int*   tok  = (const int*)d_in[0];
    const float* emb  = (const float*)d_in[1];
    const float* ln1s = (const float*)d_in[2];
    const float* ln1b = (const float*)d_in[3];
    const float* wq   = (const float*)d_in[4];
    const float* wk   = (const float*)d_in[5];
    const float* wv   = (const float*)d_in[6];
    const float* wo   = (const float*)d_in[7];
    const float* ln2s = (const float*)d_in[8];
    const float* ln2b = (const float*)d_in[9];
    const float* w1   = (const float*)d_in[10];
    const float* b1   = (const float*)d_in[11];
    const float* w2   = (const float*)d_in[12];
    const float* b2   = (const float*)d_in[13];
    const float* lnfs = (const float*)d_in[14];
    const float* lnfb = (const float*)d_in[15];

    char* ws = (char*)d_ws;
    const size_t MB = 1024 * 1024;
    float* x    = (float*)(ws);                    // [BS,512] f32 residual, 0-32MB
    u16*   h    = (u16*)(ws + 32 * MB);            // [BS,512] bf16, 32-48
    u16*   qkv  = (u16*)(ws + 48 * MB);            // [BS,1536] bf16, 48-96
    u16*   m    = qkv;                             // [BS,2048] FFN buf aliases qkv, 48-112
    float* kv   = (float*)(ws + 112 * MB);         // [B,H,64,64]
    float* z    = kv + BATCH * NH * HD * HD;
    float* maskf = (float*)(ws + 112 * MB + 768 * 1024);  // [BS]
    u16*   wt   = (u16*)(ws + 113 * MB);           // qkvoT: 4x[512][512] (2MB)
    u16*   w1t  = (u16*)(ws + 115 * MB);           // w1T [2048][512] (2MB)
    u16*   w2t  = (u16*)(ws + 117 * MB);           // w2T [512][2048] (2MB)

    embed_kernel<<<BS_TOK, 128, 0, stream>>>(tok, emb, x, maskf);

    const size_t WSTEP = (size_t)EMB * EMB;
    dim3 gQKVb(6, BS_TOK / 256);    // 256-tile: N=1536 -> 384 WGs (%8==0)
    dim3 gFF1b(8, BS_TOK / 256);    // 256-tile: N=2048 -> 512 WGs
    dim3 gN512(4, BS_TOK / 128);    // 128-tile: N=512 -> 512 WGs

    for (int l = 0; l < NL; ++l) {
        ln_kernel<u16><<<BS_TOK, 256, 0, stream>>>(x, ln1s + l * EMB, ln1b + l * EMB, h);
        transpose_w<<<dim3(16, 16, 4), 256, 0, stream>>>(
            wq + l * WSTEP, wk + l * WSTEP, wv + l * WSTEP, wo + l * WSTEP, wt, EMB, EMB);
        // fused qkv (deep-pipeline 256-tile): q=phi, k=phi*mask, v=plain
        mfma_gemm_big<3, u16><<<gQKVb, 512, 0, stream>>>(
            h, wt, nullptr, maskf, nullptr, qkv, EMB, EMB, 1536);

        hipMemsetAsync(kv, 0, (size_t)(BATCH * NH * HD * HD + BATCH * NH * HD) * sizeof(float), stream);
        kv_reduce_mfma<<<dim3(BATCH * NH, SEQ / 256), 256, 0, stream>>>(qkv + 512, qkv + 1024, kv, z, 1536);
        attn_out2<<<dim3(BS_TOK / 32, NH), 256, 0, stream>>>(qkv, kv, z, h, 1536);

        // x = x + attn_out @ wo   (2-phase kernel, N=512)
        mfma_gemm<0, float><<<gN512, 256, 0, stream>>>(
            h, wt + 3 * WSTEP, nullptr, nullptr, x, x, EMB, EMB, EMB, EMB);

        ln_kernel<u16><<<BS_TOK, 256, 0, stream>>>(x, ln2s + l * EMB, ln2b + l * EMB, h);
        const float* w1l = w1 + (size_t)l * EMB * FF;
        const float* w2l = w2 + (size_t)l * FF * EMB;
        const float* b1l = b1 + (size_t)l * FF;
        const float* b2l = b2 + (size_t)l * EMB;
        transpose_w<<<dim3(64, 16, 1), 256, 0, stream>>>(w1l, w1l, w1l, w1l, w1t, EMB, FF);  // [2048][512]
        transpose_w<<<dim3(16, 64, 1), 256, 0, stream>>>(w2l, w2l, w2l, w2l, w2t, FF, EMB);  // [512][2048]
        // m = gelu(h @ w1 + b1) (deep-pipeline 256-tile, one dispatch)
        mfma_gemm_big<1, u16><<<gFF1b, 512, 0, stream>>>(
            h, w1t, b1l, nullptr, nullptr, m, EMB, EMB, FF);
        // x += m @ w2 + b2 (2-phase kernel, K=2048, one dispatch)
        mfma_gemm<0, float><<<gN512, 256, 0, stream>>>(
            m, w2t, b2l, nullptr, x, x, FF, FF, FF, EMB);
    }

    ln_kernel<float><<<BS_TOK, 256, 0, stream>>>(x, lnfs, lnfb, (float*)d_out);
}

// Round 10
// 1713.819 us; speedup vs baseline: 1.0347x; 1.0347x over previous
//
#include <hip/hip_runtime.h>
#include <hip/hip_bf16.h>

#define BATCH 4
#define SEQ   4096
#define BS_TOK (BATCH*SEQ)   // 16384 rows
#define EMB   512
#define NH    8
#define HD    64
#define FF    2048
#define NL    6

typedef unsigned short u16;
typedef __attribute__((ext_vector_type(8))) short bf16x8;
typedef __attribute__((ext_vector_type(4))) float f32x4;

__device__ __forceinline__ float bf2f(u16 u) {
    union { unsigned int i; float f; } x; x.i = ((unsigned int)u) << 16; return x.f;
}
__device__ __forceinline__ u16 f2bf(float f) {
    __hip_bfloat16 b = __float2bfloat16(f);
    return *(u16*)&b;
}
// gelu(x) = 0.5x(1+tanh(z)), z=0.79788456(x+0.044715x^3)  ==  x / (1+e^{-2z})
__device__ __forceinline__ float gelu_fast(float x) {
    float e = __expf(x * (-1.5957691216057308f - 0.0713548162726009f * x * x));
    return x * __builtin_amdgcn_rcpf(1.f + e);
}
__device__ __forceinline__ void store_out(float* p, float v) { *p = v; }
__device__ __forceinline__ void store_out(u16* p, float v) { *p = f2bf(v); }
__device__ __forceinline__ void store_pair(float* p, float a, float b) {
    *(float2*)p = make_float2(a, b);
}
__device__ __forceinline__ void store_pair(u16* p, float a, float b) {
    unsigned int u = ((unsigned int)f2bf(b) << 16) | (unsigned int)f2bf(a);
    *(unsigned int*)p = u;
}

__device__ __forceinline__ void gl_lds16(const void* g, void* l) {
    __builtin_amdgcn_global_load_lds(
        (__attribute__((address_space(1))) void*)g,
        (__attribute__((address_space(3))) void*)l, 16, 0, 0);
}

// ---------------------------------------------------------------------------
__global__ __launch_bounds__(128) void embed_kernel(
        const int* __restrict__ tok, const float* __restrict__ emb,
        float* __restrict__ X, float* __restrict__ maskf) {
    int row = blockIdx.x;
    int t = threadIdx.x;
    int id = tok[row];
    if (t == 0) maskf[row] = (id > 0) ? 1.f : 0.f;
    int s = row & (SEQ - 1);
    int e0 = t * 4;
    float4 u = *(const float4*)(emb + (size_t)id * EMB + e0);
    float vals[4] = { u.x, u.y, u.z, u.w };
    float out[4];
#pragma unroll
    for (int j = 0; j < 4; ++j) {
        int ee = e0 + j;
        int i = ee >> 1;
        float div = expf(-0.035977892078031970f * (float)i);
        float ang = (float)s * div;
        float pe = (ee & 1) ? cosf(ang) : sinf(ang);
        out[j] = vals[j] + pe;
    }
    *(float4*)(X + (size_t)row * EMB + e0) = make_float4(out[0], out[1], out[2], out[3]);
}

// ---------------------------------------------------------------------------
// LN row kernel, vectorized (G13): float2 loads of x/sc/bi, packed 4B stores.
// ---------------------------------------------------------------------------
template<typename OUT>
__global__ __launch_bounds__(256) void ln_kernel(
        const float* __restrict__ X, const float* __restrict__ sc,
        const float* __restrict__ bi, OUT* __restrict__ Y) {
    int row = blockIdx.x, t = threadIdx.x;
    const float* x = X + (size_t)row * EMB;
    float2 v = *(const float2*)(x + 2 * t);
    float a = v.x, b = v.y;
    float s = a + b, q = a * a + b * b;
#pragma unroll
    for (int off = 32; off; off >>= 1) {
        s += __shfl_xor(s, off);
        q += __shfl_xor(q, off);
    }
    __shared__ float ss[4], qq[4];
    int w = t >> 6;
    if ((t & 63) == 0) { ss[w] = s; qq[w] = q; }
    __syncthreads();
    s = ss[0] + ss[1] + ss[2] + ss[3];
    q = qq[0] + qq[1] + qq[2] + qq[3];
    float mu = s * (1.f / 512.f);
    float var = q * (1.f / 512.f) - mu * mu;
    float rstd = rsqrtf(var + 1e-6f);
    float2 scv = *(const float2*)(sc + 2 * t);
    float2 biv = *(const float2*)(bi + 2 * t);
    float y0 = (a - mu) * rstd * scv.x + biv.x;
    float y1 = (b - mu) * rstd * scv.y + biv.y;
    store_pair(&Y[(size_t)row * EMB + 2 * t], y0, y1);
}

// ---------------------------------------------------------------------------
// Weight transpose + bf16 cast: W[K][N] f32 -> WT[N][K] bf16; z picks source
// ---------------------------------------------------------------------------
__global__ __launch_bounds__(256) void transpose_w(
        const float* __restrict__ W0, const float* __restrict__ W1,
        const float* __restrict__ W2, const float* __restrict__ W3,
        u16* __restrict__ WT, int K, int N) {
    const float* W = (blockIdx.z == 0) ? W0 : (blockIdx.z == 1) ? W1
                   : (blockIdx.z == 2) ? W2 : W3;
    u16* dst = WT + (size_t)blockIdx.z * K * N;
    __shared__ u16 tile[32][33];
    int n0 = blockIdx.x * 32, k0 = blockIdx.y * 32;
    int tx = threadIdx.x & 31, ty = threadIdx.x >> 5;
#pragma unroll
    for (int u = 0; u < 4; ++u)
        tile[ty + u * 8][tx] = f2bf(W[(size_t)(k0 + ty + u * 8) * N + n0 + tx]);
    __syncthreads();
#pragma unroll
    for (int u = 0; u < 4; ++u)
        dst[(size_t)(n0 + ty + u * 8) * K + k0 + tx] = tile[tx][ty + u * 8];
}

// ---------------------------------------------------------------------------
// 2-phase MFMA bf16 GEMM (measured-best config, r5/r7/r8): tile 128x128,
// 4 waves, BK=32 double-buffer, stage-early, one __syncthreads per step.
// Used for QKV, WO, FFN2.  [r9: 256-tile for QKV regressed -- 384 WGs at
// 1 blk/CU = 1.5 dispatch rounds, ~33% tail waste.]
// ---------------------------------------------------------------------------
template<int OP, typename OUT>
__global__ __launch_bounds__(256, 4) void mfma_gemm(
        const u16* __restrict__ A, const u16* __restrict__ BT,
        const float* __restrict__ bias, const float* __restrict__ rowscale,
        const float* __restrict__ residual, OUT* __restrict__ C,
        int K, int lda, int ldb, int ldc) {
    __shared__ u16 As[2][128 * 32];   // buffer bb: [128 rows][32 k] (64B rows)
    __shared__ u16 Bs[2][128 * 32];
    int tid = threadIdx.x;
    int wid = tid >> 6, lane = tid & 63;
    int nwg = gridDim.x * gridDim.y;
    int lin = blockIdx.y * gridDim.x + blockIdx.x;
    int swz = (nwg & 7) ? lin : ((lin & 7) * (nwg >> 3) + (lin >> 3));
    int bx = swz % gridDim.x, by = swz / gridDim.x;
    int row0 = by * 128, col0 = bx * 128;
    int wm = (wid & 1) * 64, wn = (wid >> 1) * 64;
    int quad = lane >> 4, l16 = lane & 15;

    f32x4 acc[4][4];
#pragma unroll
    for (int i = 0; i < 4; ++i)
#pragma unroll
        for (int j = 0; j < 4; ++j)
#pragma unroll
            for (int r = 0; r < 4; ++r) acc[i][j][r] = 0.f;

    int rsub = lane >> 2;
    int koff = (lane & 3) * 8;
    const u16* gA = A  + (size_t)(row0 + wid * 16 + rsub) * lda + koff;
    const u16* gB = BT + (size_t)(col0 + wid * 16 + rsub) * ldb + koff;

    auto stage = [&](int bb, int kk) {
        u16* lA = As[bb] + wid * 512;
        u16* lB = Bs[bb] + wid * 512;
#pragma unroll
        for (int i = 0; i < 2; ++i) {
            gl_lds16(gA + (size_t)(i * 64) * lda + kk, lA + i * 2048);
            gl_lds16(gB + (size_t)(i * 64) * ldb + kk, lB + i * 2048);
        }
    };

    int nt = K >> 5;           // BK=32 steps
    stage(0, 0);
    __syncthreads();           // drain prologue loads
    for (int t = 0; t < nt; ++t) {
        int cur = t & 1;
        if (t + 1 < nt) stage(cur ^ 1, (t + 1) * 32);   // issue next tile EARLY
        bf16x8 af[4], bfv[4];
#pragma unroll
        for (int i = 0; i < 4; ++i)
            af[i] = *(const bf16x8*)(As[cur] + (wm + i * 16 + l16) * 32 + quad * 8);
#pragma unroll
        for (int j = 0; j < 4; ++j)
            bfv[j] = *(const bf16x8*)(Bs[cur] + (wn + j * 16 + l16) * 32 + quad * 8);
#pragma unroll
        for (int i = 0; i < 4; ++i)
#pragma unroll
            for (int j = 0; j < 4; ++j)
                acc[i][j] = __builtin_amdgcn_mfma_f32_16x16x32_bf16(af[i], bfv[j], acc[i][j], 0, 0, 0);
        __syncthreads();
    }

    // epilogue: D mapping col = lane&15, row = quad*4 + reg (m89-verified)
    int seg = col0 >> 9;
    float bc[4];
#pragma unroll
    for (int j = 0; j < 4; ++j)
        bc[j] = bias ? bias[col0 + wn + j * 16 + l16] : 0.f;
#pragma unroll
    for (int i = 0; i < 4; ++i) {
        float res[4][4];
        if (residual) {
#pragma unroll
            for (int r = 0; r < 4; ++r) {
                size_t rb = (size_t)(row0 + wm + i * 16 + quad * 4 + r) * ldc + col0 + wn;
#pragma unroll
                for (int j = 0; j < 4; ++j)
                    res[r][j] = residual[rb + j * 16 + l16];
            }
        }
#pragma unroll
        for (int r = 0; r < 4; ++r) {
            int row = row0 + wm + i * 16 + quad * 4 + r;
            float rsv = (OP == 3 && seg == 1) ? rowscale[row] : 1.f;
            size_t rb = (size_t)row * ldc + col0 + wn;
#pragma unroll
            for (int j = 0; j < 4; ++j) {
                float val = acc[i][j][r] + bc[j];
                if (OP == 1) val = gelu_fast(val);
                if (OP == 3 && seg < 2) val = fmaxf(val, 0.f) + 1e-3f;
                if (OP == 3 && seg == 1) val *= rsv;
                size_t idx = rb + j * 16 + l16;
                if (residual) val += res[r][j];
                store_out(&C[idx], val);
            }
        }
    }
}

// ---------------------------------------------------------------------------
// Deep-pipeline MFMA GEMM, FFN1 only (K=512, N=2048 -> 512 WGs = exactly
// 2 full GPU rounds at 1 blk/CU -- r9: 61.3 vs 66.5 us on 2-phase; QKV's
// 384-WG grid regressed on this kernel and stays on mfma_gemm).
// Tile 256x256, 8 waves (2M x 4N), per-wave 128x64 (acc 8x4), BK=64.
// LDS: 2 buffers x (A,B) x [2 planes][256 rows][32 k] = 128 KB.
// Per iteration: vmcnt(8) [kt landed, kt+1 in flight]; barrier; 64 MFMA
// (4 quad-phases, compiler-lgkmcnt-separated); barrier; stage kt+2 into
// this buffer.  Static LDS addressing (two explicit buffer bodies).
// ---------------------------------------------------------------------------
template<int OP, typename OUT>
__global__ __launch_bounds__(512, 2) void mfma_gemm_big(
        const u16* __restrict__ A, const u16* __restrict__ BT,
        const float* __restrict__ bias, const float* __restrict__ rowscale,
        const float* __restrict__ residual, OUT* __restrict__ C,
        int lda, int ldb, int ldc) {
    constexpr int NKT = 8;            // K = 512 = 8 x 64
    __shared__ u16 As[2][2 * 256 * 32];
    __shared__ u16 Bs[2][2 * 256 * 32];
    int tid = threadIdx.x;
    int wid = tid >> 6, lane = tid & 63;
    int nwg = gridDim.x * gridDim.y;
    int lin = blockIdx.y * gridDim.x + blockIdx.x;
    int swz = (nwg & 7) ? lin : ((lin & 7) * (nwg >> 3) + (lin >> 3));
    int bx = swz % gridDim.x, by = swz / gridDim.x;
    int row0 = by * 256, col0 = bx * 256;
    int wm = (wid & 1) * 128;         // wave M offset (rows)
    int wn = (wid >> 1) * 64;         // wave N offset (cols)
    int quad = lane >> 4, l16 = lane & 15;

    f32x4 acc[8][4];
#pragma unroll
    for (int i = 0; i < 8; ++i)
#pragma unroll
        for (int j = 0; j < 4; ++j)
#pragma unroll
            for (int r = 0; r < 4; ++r) acc[i][j][r] = 0.f;

    // staging: thread t covers row hf*128 + (t>>2), k-piece pl*32 + (t&3)*8
    int srow = tid >> 2;
    int skp  = (tid & 3) * 8;
    const u16* gA = A  + (size_t)(row0 + srow) * lda + skp;
    const u16* gB = BT + (size_t)(col0 + srow) * ldb + skp;

    auto stage = [&](u16* lA, u16* lB, int k0) {
#pragma unroll
        for (int pl = 0; pl < 2; ++pl)
#pragma unroll
            for (int hf = 0; hf < 2; ++hf) {
                int ldsoff = pl * 8192 + hf * 4096 + tid * 8;
                gl_lds16(gA + (size_t)(hf * 128) * lda + k0 + pl * 32, lA + ldsoff);
                gl_lds16(gB + (size_t)(hf * 128) * ldb + k0 + pl * 32, lB + ldsoff);
            }
    };

    auto iter = [&](const u16* lA, const u16* lB, u16* sA, u16* sB, int kt) {
        if (kt < NKT - 1) asm volatile("s_waitcnt vmcnt(8)" ::: "memory");
        else              asm volatile("s_waitcnt vmcnt(0)" ::: "memory");
        __builtin_amdgcn_s_barrier();
        asm volatile("" ::: "memory");
        bf16x8 bfv[4][2];
#pragma unroll
        for (int nf = 0; nf < 4; ++nf)
#pragma unroll
            for (int p = 0; p < 2; ++p)
                bfv[nf][p] = *(const bf16x8*)(lB + p * 8192 + (wn + nf * 16 + l16) * 32 + quad * 8);
#pragma unroll
        for (int q = 0; q < 4; ++q) {
            bf16x8 af[2][2];
#pragma unroll
            for (int mf = 0; mf < 2; ++mf)
#pragma unroll
                for (int p = 0; p < 2; ++p)
                    af[mf][p] = *(const bf16x8*)(lA + p * 8192 + (wm + (q * 2 + mf) * 16 + l16) * 32 + quad * 8);
            __builtin_amdgcn_s_setprio(1);
#pragma unroll
            for (int mf = 0; mf < 2; ++mf)
#pragma unroll
                for (int nf = 0; nf < 4; ++nf) {
                    acc[q * 2 + mf][nf] = __builtin_amdgcn_mfma_f32_16x16x32_bf16(
                        af[mf][0], bfv[nf][0], acc[q * 2 + mf][nf], 0, 0, 0);
                    acc[q * 2 + mf][nf] = __builtin_amdgcn_mfma_f32_16x16x32_bf16(
                        af[mf][1], bfv[nf][1], acc[q * 2 + mf][nf], 0, 0, 0);
                }
            __builtin_amdgcn_s_setprio(0);
        }
        asm volatile("" ::: "memory");
        __builtin_amdgcn_s_barrier();
        asm volatile("" ::: "memory");
        if (kt + 2 < NKT) stage(sA, sB, (kt + 2) * 64);
    };

    stage(As[0], Bs[0], 0);
    stage(As[1], Bs[1], 64);
#pragma unroll 1
    for (int kt = 0; kt < NKT; kt += 2) {
        iter(As[0], Bs[0], As[0], Bs[0], kt);
        iter(As[1], Bs[1], As[1], Bs[1], kt + 1);
    }

    // epilogue: D mapping col = lane&15, row = quad*4 + reg (m89-verified)
    int seg = col0 >> 9;
    float bc[4];
#pragma unroll
    for (int nf = 0; nf < 4; ++nf)
        bc[nf] = bias ? bias[col0 + wn + nf * 16 + l16] : 0.f;
#pragma unroll
    for (int ifr = 0; ifr < 8; ++ifr) {
#pragma unroll
        for (int r = 0; r < 4; ++r) {
            int row = row0 + wm + ifr * 16 + quad * 4 + r;
            float rsv = (OP == 3 && seg == 1) ? rowscale[row] : 1.f;
            size_t rb = (size_t)row * ldc + col0 + wn;
#pragma unroll
            for (int nf = 0; nf < 4; ++nf) {
                float val = acc[ifr][nf][r] + bc[nf];
                if (OP == 1) val = gelu_fast(val);
                if (OP == 3 && seg < 2) val = fmaxf(val, 0.f) + 1e-3f;
                if (OP == 3 && seg == 1) val *= rsv;
                size_t idx = rb + nf * 16 + l16;
                if (residual) val += residual[idx];
                store_out(&C[idx], val);
            }
        }
    }
}

// ---------------------------------------------------------------------------
// MFMA kv-reduce: kv[bh][m][d] = sum_s PK[s][m]*V[s][d]; z[bh][m] = sum_s PK[s][m]
// ---------------------------------------------------------------------------
__global__ __launch_bounds__(256) void kv_reduce_mfma(
        const u16* __restrict__ PK, const u16* __restrict__ V,
        float* __restrict__ KV, float* __restrict__ Z, int ld) {
    __shared__ __align__(16) u16 pks[32][68];
    __shared__ __align__(16) u16 vvs[32][68];
    int bh = blockIdx.x;
    int b = bh >> 3, hh = bh & 7;
    int cc = blockIdx.y;
    int t = threadIdx.x;
    int wid = t >> 6, lane = t & 63;
    int quad = lane >> 4, l16 = lane & 15;
    int wm = (wid & 1) * 32, wd = (wid >> 1) * 32;

    f32x4 acc[2][2];
    f32x4 zacc[2];
#pragma unroll
    for (int i = 0; i < 2; ++i) {
#pragma unroll
        for (int j = 0; j < 2; ++j)
#pragma unroll
            for (int r = 0; r < 4; ++r) acc[i][j][r] = 0.f;
#pragma unroll
        for (int r = 0; r < 4; ++r) zacc[i][r] = 0.f;
    }
    bf16x8 ones;
#pragma unroll
    for (int e = 0; e < 8; ++e) ones[e] = (short)0x3F80;   // bf16 1.0

    int s_l = t >> 3, mo = (t & 7) * 8;
    const u16* gP = PK + (size_t)(b * SEQ + cc * 256 + s_l) * ld + hh * 64 + mo;
    const u16* gV = V  + (size_t)(b * SEQ + cc * 256 + s_l) * ld + hh * 64 + mo;
    ushort4 p0 = *(const ushort4*)gP;
    ushort4 p1 = *(const ushort4*)(gP + 4);
    ushort4 q0 = *(const ushort4*)gV;
    ushort4 q1 = *(const ushort4*)(gV + 4);

    for (int st = 0; st < 8; ++st) {
        *(ushort4*)&pks[s_l][mo]     = p0;
        *(ushort4*)&pks[s_l][mo + 4] = p1;
        *(ushort4*)&vvs[s_l][mo]     = q0;
        *(ushort4*)&vvs[s_l][mo + 4] = q1;
        __syncthreads();
        if (st < 7) {
            gP += (size_t)32 * ld;  gV += (size_t)32 * ld;
            p0 = *(const ushort4*)gP;  p1 = *(const ushort4*)(gP + 4);
            q0 = *(const ushort4*)gV;  q1 = *(const ushort4*)(gV + 4);
        }
        bf16x8 af[2], bfv[2];
#pragma unroll
        for (int i = 0; i < 2; ++i) {
#pragma unroll
            for (int e = 0; e < 8; ++e) {
                af[i][e]  = (short)pks[quad * 8 + e][wm + i * 16 + l16];
                bfv[i][e] = (short)vvs[quad * 8 + e][wd + i * 16 + l16];
            }
        }
#pragma unroll
        for (int i = 0; i < 2; ++i)
#pragma unroll
            for (int j = 0; j < 2; ++j)
                acc[i][j] = __builtin_amdgcn_mfma_f32_16x16x32_bf16(af[i], bfv[j], acc[i][j], 0, 0, 0);
        if (wid < 2) {
            zacc[0] = __builtin_amdgcn_mfma_f32_16x16x32_bf16(af[0], ones, zacc[0], 0, 0, 0);
            zacc[1] = __builtin_amdgcn_mfma_f32_16x16x32_bf16(af[1], ones, zacc[1], 0, 0, 0);
        }
        __syncthreads();
    }

#pragma unroll
    for (int i = 0; i < 2; ++i)
#pragma unroll
        for (int j = 0; j < 2; ++j)
#pragma unroll
            for (int r = 0; r < 4; ++r)
                atomicAdd(&KV[((size_t)bh * 64 + wm + i * 16 + quad * 4 + r) * 64
                              + wd + j * 16 + l16], acc[i][j][r]);
    if (wid < 2 && l16 == 0) {
#pragma unroll
        for (int i = 0; i < 2; ++i)
#pragma unroll
            for (int r = 0; r < 4; ++r)
                atomicAdd(&Z[(size_t)bh * 64 + wm + i * 16 + quad * 4 + r], zacc[i][r]);
    }
}

// ---------------------------------------------------------------------------
// out[b,s,h,d] = (phi_q . kv[:,d]) / (phi_q . z);  PQ strided by ld
// ---------------------------------------------------------------------------
__global__ __launch_bounds__(256) void attn_out2(
        const u16* __restrict__ PQ, const float* __restrict__ KV,
        const float* __restrict__ Z, u16* __restrict__ O, int ld) {
    __shared__ float kvT[64 * 65];
    __shared__ float zsh[64];
    __shared__ float phs[4][72];
    int hh = blockIdx.y;
    int row0 = blockIdx.x * 32;
    int b = row0 >> 12;
    int bh = b * NH + hh;
    int t = threadIdx.x;
    const float* kvg = KV + (size_t)bh * 4096;
#pragma unroll
    for (int u = 0; u < 16; ++u) {
        int idx = u * 256 + t;
        kvT[(idx & 63) * 65 + (idx >> 6)] = kvg[idx];
    }
    if (t < 64) zsh[t] = Z[(size_t)bh * 64 + t];
    __syncthreads();
    int wid = t >> 6, lane = t & 63;
    const float* kvrow = kvT + lane * 65;
    for (int rr = 0; rr < 8; ++rr) {
        int row = row0 + wid * 8 + rr;
        float p = bf2f(PQ[(size_t)row * ld + hh * 64 + lane]);
        float d = p * zsh[lane];
#pragma unroll
        for (int off = 32; off; off >>= 1) d += __shfl_xor(d, off);
        d = fmaxf(d, 1e-20f);
        phs[wid][lane] = p;
        float acc = 0.f;
#pragma unroll
        for (int mm = 0; mm < 64; ++mm)
            acc = fmaf(phs[wid][mm], kvrow[mm], acc);
        O[(size_t)row * EMB + hh * 64 + lane] = f2bf(acc / d);
    }
}

// ---------------------------------------------------------------------------
extern "C" void kernel_launch(void* const* d_in, const int* in_sizes, int n_in,
                              void* d_out, int out_size, void* d_ws, size_t ws_size,
                              hipStream_t stream) {
    (void)in_sizes; (void)n_in; (void)out_size; (void)ws_size;
    const int*   tok  = (const int*)d_in[0];
    const float* emb  = (const float*)d_in[1];
    const float* ln1s = (const float*)d_in[2];
    const float* ln1b = (const float*)d_in[3];
    const float* wq   = (const float*)d_in[4];
    const float* wk   = (const float*)d_in[5];
    const float* wv   = (const float*)d_in[6];
    const float* wo   = (const float*)d_in[7];
    const float* ln2s = (const float*)d_in[8];
    const float* ln2b = (const float*)d_in[9];
    const float* w1   = (const float*)d_in[10];
    const float* b1   = (const float*)d_in[11];
    const float* w2   = (const float*)d_in[12];
    const float* b2   = (const float*)d_in[13];
    const float* lnfs = (const float*)d_in[14];
    const float* lnfb = (const float*)d_in[15];

    char* ws = (char*)d_ws;
    const size_t MB = 1024 * 1024;
    float* x    = (float*)(ws);                    // [BS,512] f32 residual, 0-32MB
    u16*   h    = (u16*)(ws + 32 * MB);            // [BS,512] bf16, 32-48
    u16*   qkv  = (u16*)(ws + 48 * MB);            // [BS,1536] bf16, 48-96
    u16*   m    = qkv;                             // [BS,2048] FFN buf aliases qkv, 48-112
    float* kv   = (float*)(ws + 112 * MB);         // [B,H,64,64]
    float* z    = kv + BATCH * NH * HD * HD;
    float* maskf = (float*)(ws + 112 * MB + 768 * 1024);  // [BS]
    u16*   wt   = (u16*)(ws + 113 * MB);           // qkvoT: 4x[512][512] (2MB)
    u16*   w1t  = (u16*)(ws + 115 * MB);           // w1T [2048][512] (2MB)
    u16*   w2t  = (u16*)(ws + 117 * MB);           // w2T [512][2048] (2MB)

    embed_kernel<<<BS_TOK, 128, 0, stream>>>(tok, emb, x, maskf);

    const size_t WSTEP = (size_t)EMB * EMB;
    dim3 gQKV(12, BS_TOK / 128);    // 128-tile: N=1536 -> 1536 WGs (%8==0)
    dim3 gFF1b(8, BS_TOK / 256);    // 256-tile: N=2048 -> 512 WGs (2 full rounds)
    dim3 gN512(4, BS_TOK / 128);    // 128-tile: N=512 -> 512 WGs

    for (int l = 0; l < NL; ++l) {
        ln_kernel<u16><<<BS_TOK, 256, 0, stream>>>(x, ln1s + l * EMB, ln1b + l * EMB, h);
        transpose_w<<<dim3(16, 16, 4), 256, 0, stream>>>(
            wq + l * WSTEP, wk + l * WSTEP, wv + l * WSTEP, wo + l * WSTEP, wt, EMB, EMB);
        // fused qkv (2-phase 128-tile): q=phi, k=phi*mask, v=plain
        mfma_gemm<3, u16><<<gQKV, 256, 0, stream>>>(
            h, wt, nullptr, maskf, nullptr, qkv, EMB, EMB, EMB, 1536);

        hipMemsetAsync(kv, 0, (size_t)(BATCH * NH * HD * HD + BATCH * NH * HD) * sizeof(float), stream);
        kv_reduce_mfma<<<dim3(BATCH * NH, SEQ / 256), 256, 0, stream>>>(qkv + 512, qkv + 1024, kv, z, 1536);
        attn_out2<<<dim3(BS_TOK / 32, NH), 256, 0, stream>>>(qkv, kv, z, h, 1536);

        // x = x + attn_out @ wo   (2-phase kernel, N=512)
        mfma_gemm<0, float><<<gN512, 256, 0, stream>>>(
            h, wt + 3 * WSTEP, nullptr, nullptr, x, x, EMB, EMB, EMB, EMB);

        ln_kernel<u16><<<BS_TOK, 256, 0, stream>>>(x, ln2s + l * EMB, ln2b + l * EMB, h);
        const float* w1l = w1 + (size_t)l * EMB * FF;
        const float* w2l = w2 + (size_t)l * FF * EMB;
        const float* b1l = b1 + (size_t)l * FF;
        const float* b2l = b2 + (size_t)l * EMB;
        transpose_w<<<dim3(64, 16, 1), 256, 0, stream>>>(w1l, w1l, w1l, w1l, w1t, EMB, FF);  // [2048][512]
        transpose_w<<<dim3(16, 64, 1), 256, 0, stream>>>(w2l, w2l, w2l, w2l, w2t, FF, EMB);  // [512][2048]
        // m = gelu(h @ w1 + b1) (deep-pipeline 256-tile, one dispatch)
        mfma_gemm_big<1, u16><<<gFF1b, 512, 0, stream>>>(
            h, w1t, b1l, nullptr, nullptr, m, EMB, EMB, FF);
        // x += m @ w2 + b2 (2-phase kernel, K=2048, one dispatch)
        mfma_gemm<0, float><<<gN512, 256, 0, stream>>>(
            m, w2t, b2l, nullptr, x, x, FF, FF, FF, EMB);
    }

    ln_kernel<float><<<BS_TOK, 256, 0, stream>>>(x, lnfs, lnfb, (float*)d_out);
}